// Round 4
// baseline (1308.398 us; speedup 1.0000x reference)
//
#include <hip/hip_runtime.h>
#include <math.h>

// leaky_current_RNN: B=128, T=512, I=4, H=512, O=3, alpha=0.5, n_reg=256.
// R4: (1) amdgpu_waves_per_eu(2,2) pins the allocator budget to 256 VGPRs so
// the 128 named weight floats actually stay register-resident (R2/R3 spilled
// at 80-88 VGPRs chasing useless occupancy -- grid is 1 block/CU);
// (2) exchange buffer pairs row0/row1 per column so consumers poll with ONE
// coherent 16B global_load_dwordx4 sc1 (inline asm) per lane.

#define BB 128
#define TT 512
#define II 4
#define HH 512
#define OO 3
#define NREG_ 256

#define NTHREADS 512
#define MEMBERS 4
#define ROWS 2
#define NGROUPS 64
#define NBLOCKS (NGROUPS * MEMBERS)

typedef unsigned long long u64;
typedef unsigned int u32;
typedef __attribute__((ext_vector_type(4))) u32 u32x4;

__device__ __forceinline__ void astore(u64* p, u64 v) {
    __hip_atomic_store(p, v, __ATOMIC_RELAXED, __HIP_MEMORY_SCOPE_AGENT);
}
__device__ __forceinline__ float rlane(float v, int l) {
    return __uint_as_float(__builtin_amdgcn_readlane(__float_as_uint(v), l));
}

#define R16(M) M(0) M(1) M(2) M(3) M(4) M(5) M(6) M(7) \
               M(8) M(9) M(10) M(11) M(12) M(13) M(14) M(15)

// W slice load: wa = cols [memb*128+lane], wb = cols [memb*128+64+lane]
#define WLD(Q) \
    float4 wa##Q, wb##Q; \
    wa##Q.x = Wp[(size_t)(4*Q+0)*HH];      wa##Q.y = Wp[(size_t)(4*Q+1)*HH]; \
    wa##Q.z = Wp[(size_t)(4*Q+2)*HH];      wa##Q.w = Wp[(size_t)(4*Q+3)*HH]; \
    wb##Q.x = Wp[(size_t)(4*Q+0)*HH + 64]; wb##Q.y = Wp[(size_t)(4*Q+1)*HH + 64]; \
    wb##Q.z = Wp[(size_t)(4*Q+2)*HH + 64]; wb##Q.w = Wp[(size_t)(4*Q+3)*HH + 64];

#define MV(Q) \
    { float s0 = rlane(ar0, 4*Q+0), s1 = rlane(ar1, 4*Q+0); \
      acc00 = fmaf(s0, wa##Q.x, acc00); acc01 = fmaf(s0, wb##Q.x, acc01); \
      acc10 = fmaf(s1, wa##Q.x, acc10); acc11 = fmaf(s1, wb##Q.x, acc11); } \
    { float s0 = rlane(ar0, 4*Q+1), s1 = rlane(ar1, 4*Q+1); \
      acc00 = fmaf(s0, wa##Q.y, acc00); acc01 = fmaf(s0, wb##Q.y, acc01); \
      acc10 = fmaf(s1, wa##Q.y, acc10); acc11 = fmaf(s1, wb##Q.y, acc11); } \
    { float s0 = rlane(ar0, 4*Q+2), s1 = rlane(ar1, 4*Q+2); \
      acc00 = fmaf(s0, wa##Q.z, acc00); acc01 = fmaf(s0, wb##Q.z, acc01); \
      acc10 = fmaf(s1, wa##Q.z, acc10); acc11 = fmaf(s1, wb##Q.z, acc11); } \
    { float s0 = rlane(ar0, 4*Q+3), s1 = rlane(ar1, 4*Q+3); \
      acc00 = fmaf(s0, wa##Q.w, acc00); acc01 = fmaf(s0, wb##Q.w, acc01); \
      acc10 = fmaf(s1, wa##Q.w, acc10); acc11 = fmaf(s1, wb##Q.w, acc11); }

// abuf layout: [slot][group][col][row] of u64 (value,tag):
//   idx = ((slot*NGROUPS + group)*HH + col)*2 + row   -- 16B per column.
__global__ __launch_bounds__(NTHREADS) __attribute__((amdgpu_waves_per_eu(2, 2)))
void rnn_main(const float* __restrict__ x,
              const float* __restrict__ h0,
              const float* __restrict__ W_rec,
              const float* __restrict__ W_in,
              const float* __restrict__ bias_rec,
              const float* __restrict__ bias_in,
              float* __restrict__ hidden,      // (T+1, B, H) region of d_out
              u64* __restrict__ abuf,          // exchange buffer in d_ws
              float* __restrict__ partials)
{
    const int tid  = threadIdx.x;
    const int bid  = blockIdx.x;
    const int xcd  = bid & 7;
    const int onx  = bid >> 3;
    const int memb = onx & (MEMBERS - 1);
    const int group = xcd * 8 + (onx >> 2);   // 0..63
    const int r0   = group * ROWS;
    const int wid  = tid >> 6;                // k-chunk: k in [64*wid, 64*wid+64)
    const int lane = tid & 63;

    __shared__ float sc_s[ROWS][128][9];      // split-k partials (pad 9)
    __shared__ float xbuf[ROWS * TT * II];
    __shared__ float win_s[II][128];
    __shared__ float ub_s[128];
    __shared__ float red_s[NTHREADS / 64];

    // ---- one-time staging ----
    for (int idx = tid; idx < ROWS * TT * II; idx += NTHREADS) {
        int r = idx >> 11, rem = idx & (TT * II - 1);
        xbuf[idx] = x[(size_t)(r0 + r) * (TT * II) + rem];
    }
    if (tid < II * 128) {
        int i = tid >> 7, jj = tid & 127;
        win_s[i][jj] = W_in[i * HH + memb * 128 + jj];
    }
    if (tid < 128) {
        ub_s[tid] = bias_rec[memb * 128 + tid] + bias_in[memb * 128 + tid];
    }

    // ---- W_rec slice into NAMED registers (coalesced one-time loads) ----
    const float* Wp = W_rec + (size_t)(wid * 64) * HH + memb * 128 + lane;
    R16(WLD)

    // ---- finalize-thread state + initial production (tag 1 = tanh(h0)) ----
    const int fr  = tid >> 7;           // valid when tid < 256
    const int fj  = tid & 127;
    const int fjg = memb * 128 + fj;
    float hprev = 0.0f, zprev = 0.0f, racc = 0.0f;
    if (tid < ROWS * 128) {
        hprev = h0[(size_t)(r0 + fr) * HH + fjg];
        float a0v = tanhf(hprev);
        u64 pv = (u64)__float_as_uint(a0v) | ((u64)1u << 32);
        astore(&abuf[((size_t)(0 * NGROUPS + group) * HH + fjg) * 2 + fr], pv);
        hidden[(size_t)(r0 + fr) * HH + fjg] = hprev;   // hidden[0] = h0
    }

#pragma unroll 1
    for (int t = 0; t < TT; ++t) {
        const int slot = t & 1;
        const u32 tagc = (u32)(t + 1);
        const u32 tagp = (u32)(t + 2);

        // ---- poll own activation window: one coherent 16B load per lane ----
        const u64* pp = abuf +
            ((size_t)(slot * NGROUPS + group) * HH + wid * 64 + lane) * 2;
        u32x4 v;
        for (;;) {
            asm volatile("global_load_dwordx4 %0, %1, off sc1\n\t"
                         "s_waitcnt vmcnt(0)"
                         : "=v"(v) : "v"(pp) : "memory");
            if (__all((v.y == tagc) && (v.w == tagc))) break;
        }
        float ar0 = __uint_as_float(v.x);   // a[row0][64*wid + lane]
        float ar1 = __uint_as_float(v.z);   // a[row1][64*wid + lane]

        // ---- matvec: readlane broadcast x register weights ----
        float acc00 = 0.0f, acc01 = 0.0f, acc10 = 0.0f, acc11 = 0.0f;
        R16(MV)

        sc_s[0][lane][wid]      = acc00;
        sc_s[0][lane + 64][wid] = acc01;
        sc_s[1][lane][wid]      = acc10;
        sc_s[1][lane + 64][wid] = acc11;
        __syncthreads();

        // ---- finalize (waves 0-3): reduce, z, h_new, publish ----
        if (tid < ROWS * 128) {
            float q0 = sc_s[fr][fj][0], q1 = sc_s[fr][fj][1];
            float q2 = sc_s[fr][fj][2], q3 = sc_s[fr][fj][3];
            float q4 = sc_s[fr][fj][4], q5 = sc_s[fr][fj][5];
            float q6 = sc_s[fr][fj][6], q7 = sc_s[fr][fj][7];
            float z = ((q0 + q1) + (q2 + q3)) + ((q4 + q5) + (q6 + q7));
            z += ub_s[fj];
            const float* xr = &xbuf[fr * (TT * II) + t * II];
            z = fmaf(xr[0], win_s[0][fj], z);
            z = fmaf(xr[1], win_s[1][fj], z);
            z = fmaf(xr[2], win_s[2][fj], z);
            z = fmaf(xr[3], win_s[3][fj], z);
            float hn = 0.5f * hprev + 0.5f * z;
            float av = tanhf(hn);
            u64 pv = (u64)__float_as_uint(av) | ((u64)tagp << 32);
            astore(&abuf[((size_t)(((t + 1) & 1) * NGROUPS + group) * HH + fjg) * 2 + fr], pv);
            hidden[(size_t)(t + 1) * BB * HH + (size_t)(r0 + fr) * HH + fjg] = hn;
            if (fjg < NREG_) {
                float d1 = hn - hprev;
                racc = fmaf(d1, d1, racc);
                if (t > 0) { float d2 = z - zprev; racc = fmaf(d2, d2, racc); }
                zprev = z;
            }
            hprev = hn;
        }
        __syncthreads();   // protect sc_s for next step
    }

    // ---- block-reduce reg partial ----
    for (int off = 32; off; off >>= 1) racc += __shfl_down(racc, off);
    if ((tid & 63) == 0) red_s[tid >> 6] = racc;
    __syncthreads();
    if (tid == 0) {
        float s = 0.0f;
        for (int i = 0; i < NTHREADS / 64; ++i) s += red_s[i];
        partials[bid] = s;
    }
}

// outputs[b][t][:] = hidden[t+1][b][:] @ W_out   (one wave per (b,t))
__global__ __launch_bounds__(256)
void rnn_out(const float* __restrict__ hidden,
             const float* __restrict__ W_out,
             float* __restrict__ outputs)
{
    __shared__ float wout_s[HH * OO];
    const int tid = threadIdx.x;
    for (int i = tid; i < HH * OO; i += 256) wout_s[i] = W_out[i];
    __syncthreads();

    const int gid  = blockIdx.x * 4 + (tid >> 6);
    const int lane = tid & 63;
    const int b = gid >> 9;
    const int t = gid & (TT - 1);
    const float* hp = hidden + (size_t)(t + 1) * BB * HH + (size_t)b * HH;

    float o0 = 0.0f, o1 = 0.0f, o2 = 0.0f;
#pragma unroll
    for (int q = 0; q < 8; ++q) {
        int k = lane + 64 * q;
        float hv = hp[k];
        o0 = fmaf(hv, wout_s[k * 3 + 0], o0);
        o1 = fmaf(hv, wout_s[k * 3 + 1], o1);
        o2 = fmaf(hv, wout_s[k * 3 + 2], o2);
    }
    for (int off = 32; off; off >>= 1) {
        o0 += __shfl_down(o0, off);
        o1 += __shfl_down(o1, off);
        o2 += __shfl_down(o2, off);
    }
    if (lane == 0) {
        float* op = outputs + (size_t)(b * TT + t) * OO;
        op[0] = o0; op[1] = o1; op[2] = o2;
    }
}

__global__ __launch_bounds__(256)
void rnn_tcr(const float* __restrict__ partials, float* __restrict__ tcr)
{
    __shared__ float red[4];
    const int tid = threadIdx.x;
    float v = partials[tid];   // NBLOCKS == 256 == blockDim
    for (int off = 32; off; off >>= 1) v += __shfl_down(v, off);
    if ((tid & 63) == 0) red[tid >> 6] = v;
    __syncthreads();
    if (tid == 0) {
        float s = red[0] + red[1] + red[2] + red[3];
        *tcr = s * (1.0f / ((float)TT * (float)BB * (float)NREG_));
    }
}

extern "C" void kernel_launch(void* const* d_in, const int* in_sizes, int n_in,
                              void* d_out, int out_size, void* d_ws, size_t ws_size,
                              hipStream_t stream)
{
    (void)in_sizes; (void)n_in; (void)out_size; (void)ws_size;

    const float* x     = (const float*)d_in[0];
    const float* h0    = (const float*)d_in[1];
    const float* W_rec = (const float*)d_in[2];
    const float* W_in  = (const float*)d_in[3];
    const float* W_out = (const float*)d_in[4];
    const float* brec  = (const float*)d_in[5];
    const float* bin   = (const float*)d_in[6];

    float* out     = (float*)d_out;
    float* outputs = out;                                   // (B,T,O)
    float* hidden  = out + (size_t)BB * TT * OO;            // (T+1,B,H)
    float* tcr     = out + (size_t)BB * TT * OO + (size_t)(TT + 1) * BB * HH;

    u64* abuf = (u64*)d_ws;                                 // 2*64*512*2 u64 = 1 MB
    const size_t abuf_bytes = (size_t)2 * NGROUPS * HH * 2 * sizeof(u64);
    float* partials = (float*)((char*)d_ws + abuf_bytes);

    // zero exchange-buffer tags every call (graph replays reuse d_ws)
    (void)hipMemsetAsync(d_ws, 0, abuf_bytes, stream);

    void* args[] = { (void*)&x, (void*)&h0, (void*)&W_rec, (void*)&W_in,
                     (void*)&brec, (void*)&bin, (void*)&hidden,
                     (void*)&abuf, (void*)&partials };
    (void)hipLaunchCooperativeKernel((const void*)rnn_main,
                                     dim3(NBLOCKS), dim3(NTHREADS),
                                     args, 0, stream);

    rnn_out<<<dim3((BB * TT) / 4), dim3(256), 0, stream>>>(hidden, W_out, outputs);
    rnn_tcr<<<dim3(1), dim3(256), 0, stream>>>(partials, tcr);
}

// Round 5
// 1011.729 us; speedup vs baseline: 1.2932x; 1.2932x over previous
//
#include <hip/hip_runtime.h>
#include <math.h>

// leaky_current_RNN: B=128, T=512, I=4, H=512, O=3, alpha=0.5, n_reg=256.
// R5: (1) poll reverted to R3's paired b64 agent-atomic loads (R4's sc1
// dwordx4 poll caused 263MB of HBM writebacks = regression); (2) matvec via
// v_pk_fma_f32 inline asm -- (row0,row1) packed accumulators, (a0,a1) SGPR
// pair from the two readlanes, float2 (colA,colB) weights consumed twice with
// op_sel half-selection: 4 VALU instr/k vs ~6-8; (3) single barrier/step via
// double-buffered sc_s; (4) fast tanh (exp+rcp) on the producer serial path.

#define BB 128
#define TT 512
#define II 4
#define HH 512
#define OO 3
#define NREG_ 256

#define NTHREADS 512
#define MEMBERS 4
#define ROWS 2
#define NGROUPS 64
#define NBLOCKS (NGROUPS * MEMBERS)

typedef unsigned long long u64;
typedef unsigned int u32;
typedef __attribute__((ext_vector_type(2))) float f32x2;

__device__ __forceinline__ u64 aload(const u64* p) {
    return __hip_atomic_load(p, __ATOMIC_RELAXED, __HIP_MEMORY_SCOPE_AGENT);
}
__device__ __forceinline__ void astore(u64* p, u64 v) {
    __hip_atomic_store(p, v, __ATOMIC_RELAXED, __HIP_MEMORY_SCOPE_AGENT);
}
__device__ __forceinline__ float fast_tanh(float x) {
    float ax = fabsf(x);
    float e  = __expf(2.0f * ax);
    float r  = 1.0f - 2.0f * __builtin_amdgcn_rcpf(e + 1.0f);
    return copysignf(r, x);
}

#define R16(M) M(0) M(1) M(2) M(3) M(4) M(5) M(6) M(7) \
               M(8) M(9) M(10) M(11) M(12) M(13) M(14) M(15)

// Weight pairs: w.x = W[k][memb*128+lane], w.y = W[k][memb*128+64+lane]
#define WLD(Q) \
    f32x2 w##Q##a, w##Q##b, w##Q##c, w##Q##d; \
    w##Q##a.x = Wp[(size_t)(4*Q+0)*HH]; w##Q##a.y = Wp[(size_t)(4*Q+0)*HH+64]; \
    w##Q##b.x = Wp[(size_t)(4*Q+1)*HH]; w##Q##b.y = Wp[(size_t)(4*Q+1)*HH+64]; \
    w##Q##c.x = Wp[(size_t)(4*Q+2)*HH]; w##Q##c.y = Wp[(size_t)(4*Q+2)*HH+64]; \
    w##Q##d.x = Wp[(size_t)(4*Q+3)*HH]; w##Q##d.y = Wp[(size_t)(4*Q+3)*HH+64];

// accA = (row0*colA, row1*colA), accB = (row0*colB, row1*colB).
// pk1: src1 lo-half (w.x) for both result halves (op_sel_hi[1]=0).
// pk2: src1 hi-half (w.y) for both (op_sel[1]=1, op_sel_hi[1]=1).
#define KSTEP(K, W) { \
    u32 a0_ = __builtin_amdgcn_readlane(__float_as_uint(ar0), (K)); \
    u32 a1_ = __builtin_amdgcn_readlane(__float_as_uint(ar1), (K)); \
    u64 ab_ = (u64)a0_ | ((u64)a1_ << 32); \
    asm("v_pk_fma_f32 %0, %2, %3, %0 op_sel_hi:[1,0,1]\n\t" \
        "v_pk_fma_f32 %1, %2, %3, %1 op_sel:[0,1,0] op_sel_hi:[1,1,1]" \
        : "+v"(accA), "+v"(accB) : "s"(ab_), "v"(W)); }

#define MV(Q) KSTEP(4*Q+0, w##Q##a) KSTEP(4*Q+1, w##Q##b) \
              KSTEP(4*Q+2, w##Q##c) KSTEP(4*Q+3, w##Q##d)

// abuf layout (R3): [slot][B][H] of u64 (value, tag); row1 at +HH.
__global__ __launch_bounds__(NTHREADS) __attribute__((amdgpu_waves_per_eu(2, 2)))
void rnn_main(const float* __restrict__ x,
              const float* __restrict__ h0,
              const float* __restrict__ W_rec,
              const float* __restrict__ W_in,
              const float* __restrict__ bias_rec,
              const float* __restrict__ bias_in,
              float* __restrict__ hidden,      // (T+1, B, H) region of d_out
              u64* __restrict__ abuf,          // [2][B][H] exchange buffer
              float* __restrict__ partials)
{
    const int tid  = threadIdx.x;
    const int bid  = blockIdx.x;
    const int xcd  = bid & 7;
    const int onx  = bid >> 3;
    const int memb = onx & (MEMBERS - 1);
    const int group = xcd * 8 + (onx >> 2);   // 0..63
    const int r0   = group * ROWS;
    const int wid  = tid >> 6;                // k-window [64*wid, 64*wid+64)
    const int lane = tid & 63;

    __shared__ float sc_s[2][ROWS][128][9];   // double-buffered split-k partials
    __shared__ float xbuf[ROWS * TT * II];
    __shared__ float win_s[II][128];
    __shared__ float ub_s[128];
    __shared__ float red_s[NTHREADS / 64];

    // ---- one-time staging ----
    for (int idx = tid; idx < ROWS * TT * II; idx += NTHREADS) {
        int r = idx >> 11, rem = idx & (TT * II - 1);
        xbuf[idx] = x[(size_t)(r0 + r) * (TT * II) + rem];
    }
    if (tid < II * 128) {
        int i = tid >> 7, jj = tid & 127;
        win_s[i][jj] = W_in[i * HH + memb * 128 + jj];
    }
    if (tid < 128) {
        ub_s[tid] = bias_rec[memb * 128 + tid] + bias_in[memb * 128 + tid];
    }

    // ---- W_rec slice into registers as float2 (colA,colB) pairs ----
    const float* Wp = W_rec + (size_t)(wid * 64) * HH + memb * 128 + lane;
    R16(WLD)

    // ---- finalize-thread state + initial production (tag 1 = tanh(h0)) ----
    const int fr  = tid >> 7;           // valid when tid < 256
    const int fj  = tid & 127;
    const int fjg = memb * 128 + fj;
    float hprev = 0.0f, zprev = 0.0f, racc = 0.0f;
    if (tid < ROWS * 128) {
        hprev = h0[(size_t)(r0 + fr) * HH + fjg];
        float a0v = fast_tanh(hprev);
        u64 pv = (u64)__float_as_uint(a0v) | ((u64)1u << 32);
        astore(&abuf[((size_t)(0 * BB + r0 + fr)) * HH + fjg], pv);
        hidden[(size_t)(r0 + fr) * HH + fjg] = hprev;   // hidden[0] = h0
    }

#pragma unroll 1
    for (int t = 0; t < TT; ++t) {
        const int slot = t & 1;
        const u32 tagc = (u32)(t + 1);
        const u32 tagp = (u32)(t + 2);

        // ---- poll own activation window (R3-style paired b64 loads) ----
        const u64* p0 = abuf + ((size_t)(slot * BB + r0)) * HH + wid * 64 + lane;
        const u64* p1 = p0 + HH;
        u64 u0, u1;
        for (;;) {
            u0 = aload(p0);
            u1 = aload(p1);
            bool ok = ((u32)(u0 >> 32) == tagc) & ((u32)(u1 >> 32) == tagc);
            if (__all(ok)) break;
        }
        float ar0 = __uint_as_float((u32)u0);   // a[row0][64*wid + lane]
        float ar1 = __uint_as_float((u32)u1);   // a[row1][64*wid + lane]

        // ---- matvec: pk_fma with packed-row accumulators ----
        f32x2 accA = {0.0f, 0.0f};   // (row0, row1) x colA = lane
        f32x2 accB = {0.0f, 0.0f};   // (row0, row1) x colB = lane+64
        R16(MV)

        sc_s[slot][0][lane][wid]      = accA.x;
        sc_s[slot][1][lane][wid]      = accA.y;
        sc_s[slot][0][lane + 64][wid] = accB.x;
        sc_s[slot][1][lane + 64][wid] = accB.y;
        __syncthreads();   // single barrier per step (sc_s double-buffered)

        // ---- finalize (waves 0-3): reduce, z, h_new, publish ----
        if (tid < ROWS * 128) {
            float q0 = sc_s[slot][fr][fj][0], q1 = sc_s[slot][fr][fj][1];
            float q2 = sc_s[slot][fr][fj][2], q3 = sc_s[slot][fr][fj][3];
            float q4 = sc_s[slot][fr][fj][4], q5 = sc_s[slot][fr][fj][5];
            float q6 = sc_s[slot][fr][fj][6], q7 = sc_s[slot][fr][fj][7];
            float z = ((q0 + q1) + (q2 + q3)) + ((q4 + q5) + (q6 + q7));
            z += ub_s[fj];
            const float* xr = &xbuf[fr * (TT * II) + t * II];
            z = fmaf(xr[0], win_s[0][fj], z);
            z = fmaf(xr[1], win_s[1][fj], z);
            z = fmaf(xr[2], win_s[2][fj], z);
            z = fmaf(xr[3], win_s[3][fj], z);
            float hn = 0.5f * hprev + 0.5f * z;
            float av = fast_tanh(hn);
            u64 pv = (u64)__float_as_uint(av) | ((u64)tagp << 32);
            astore(&abuf[((size_t)(((t + 1) & 1) * BB + r0 + fr)) * HH + fjg], pv);
            hidden[(size_t)(t + 1) * BB * HH + (size_t)(r0 + fr) * HH + fjg] = hn;
            if (fjg < NREG_) {
                float d1 = hn - hprev;
                racc = fmaf(d1, d1, racc);
                if (t > 0) { float d2 = z - zprev; racc = fmaf(d2, d2, racc); }
                zprev = z;
            }
            hprev = hn;
        }
        // no tail barrier: sc_s[t^1] is free; publishes of t+1 gate overwrite
    }

    // ---- block-reduce reg partial ----
    for (int off = 32; off; off >>= 1) racc += __shfl_down(racc, off);
    if ((tid & 63) == 0) red_s[tid >> 6] = racc;
    __syncthreads();
    if (tid == 0) {
        float s = 0.0f;
        for (int i = 0; i < NTHREADS / 64; ++i) s += red_s[i];
        partials[bid] = s;
    }
}

// outputs[b][t][:] = hidden[t+1][b][:] @ W_out   (one wave per (b,t))
__global__ __launch_bounds__(256)
void rnn_out(const float* __restrict__ hidden,
             const float* __restrict__ W_out,
             float* __restrict__ outputs)
{
    __shared__ float wout_s[HH * OO];
    const int tid = threadIdx.x;
    for (int i = tid; i < HH * OO; i += 256) wout_s[i] = W_out[i];
    __syncthreads();

    const int gid  = blockIdx.x * 4 + (tid >> 6);
    const int lane = tid & 63;
    const int b = gid >> 9;
    const int t = gid & (TT - 1);
    const float* hp = hidden + (size_t)(t + 1) * BB * HH + (size_t)b * HH;

    float o0 = 0.0f, o1 = 0.0f, o2 = 0.0f;
#pragma unroll
    for (int q = 0; q < 8; ++q) {
        int k = lane + 64 * q;
        float hv = hp[k];
        o0 = fmaf(hv, wout_s[k * 3 + 0], o0);
        o1 = fmaf(hv, wout_s[k * 3 + 1], o1);
        o2 = fmaf(hv, wout_s[k * 3 + 2], o2);
    }
    for (int off = 32; off; off >>= 1) {
        o0 += __shfl_down(o0, off);
        o1 += __shfl_down(o1, off);
        o2 += __shfl_down(o2, off);
    }
    if (lane == 0) {
        float* op = outputs + (size_t)(b * TT + t) * OO;
        op[0] = o0; op[1] = o1; op[2] = o2;
    }
}

__global__ __launch_bounds__(256)
void rnn_tcr(const float* __restrict__ partials, float* __restrict__ tcr)
{
    __shared__ float red[4];
    const int tid = threadIdx.x;
    float v = partials[tid];   // NBLOCKS == 256 == blockDim
    for (int off = 32; off; off >>= 1) v += __shfl_down(v, off);
    if ((tid & 63) == 0) red[tid >> 6] = v;
    __syncthreads();
    if (tid == 0) {
        float s = red[0] + red[1] + red[2] + red[3];
        *tcr = s * (1.0f / ((float)TT * (float)BB * (float)NREG_));
    }
}

extern "C" void kernel_launch(void* const* d_in, const int* in_sizes, int n_in,
                              void* d_out, int out_size, void* d_ws, size_t ws_size,
                              hipStream_t stream)
{
    (void)in_sizes; (void)n_in; (void)out_size; (void)ws_size;

    const float* x     = (const float*)d_in[0];
    const float* h0    = (const float*)d_in[1];
    const float* W_rec = (const float*)d_in[2];
    const float* W_in  = (const float*)d_in[3];
    const float* W_out = (const float*)d_in[4];
    const float* brec  = (const float*)d_in[5];
    const float* bin   = (const float*)d_in[6];

    float* out     = (float*)d_out;
    float* outputs = out;                                   // (B,T,O)
    float* hidden  = out + (size_t)BB * TT * OO;            // (T+1,B,H)
    float* tcr     = out + (size_t)BB * TT * OO + (size_t)(TT + 1) * BB * HH;

    u64* abuf = (u64*)d_ws;                                 // 2*B*H u64 = 1 MB
    const size_t abuf_bytes = (size_t)2 * BB * HH * sizeof(u64);
    float* partials = (float*)((char*)d_ws + abuf_bytes);

    // zero exchange-buffer tags every call (graph replays reuse d_ws)
    (void)hipMemsetAsync(d_ws, 0, abuf_bytes, stream);

    void* args[] = { (void*)&x, (void*)&h0, (void*)&W_rec, (void*)&W_in,
                     (void*)&brec, (void*)&bin, (void*)&hidden,
                     (void*)&abuf, (void*)&partials };
    (void)hipLaunchCooperativeKernel((const void*)rnn_main,
                                     dim3(NBLOCKS), dim3(NTHREADS),
                                     args, 0, stream);

    rnn_out<<<dim3((BB * TT) / 4), dim3(256), 0, stream>>>(hidden, W_out, outputs);
    rnn_tcr<<<dim3(1), dim3(256), 0, stream>>>(partials, tcr);
}